// Round 1
// baseline (243.415 us; speedup 1.0000x reference)
//
#include <hip/hip_runtime.h>
#include <cstdint>
#include <cstddef>

typedef _Float16 f16;
typedef _Float16 f16x4 __attribute__((ext_vector_type(4)));
typedef _Float16 f16x8 __attribute__((ext_vector_type(8)));
typedef float    f32x4 __attribute__((ext_vector_type(4)));

#define CIN    128
#define COUT   256
#define HH     56
#define WW     56
#define HW     3136           // 56*56
#define PPDIM  3364           // 58*58 padded pixel plane
#define XPLANE (PPDIM*CIN)    // 430592 halves per batch image

// ---------------------------------------------------------------------------
// Prepass 1: x (NCHW f32) -> zero-padded NHWC f16.
// xp[b][pp][c], pp = (h+1)*58 + w + 1. Row stride 58 with shared zero columns
// means every conv tap (dh,dw) is just a flat offset (dh*58+dw)*128 — border
// zeros come from the padding, so the GEMM kernel needs NO masking at all.
// ---------------------------------------------------------------------------
__global__ __launch_bounds__(256) void xpad_kernel(const float* __restrict__ x,
                                                   f16* __restrict__ xp) {
  int bid  = blockIdx.x;                  // 32*56*2 = 3584 blocks
  int cblk = bid & 1;
  int h    = (bid >> 1) % HH;
  int b    = bid / (2*HH);
  int c0   = cblk * 64;
  __shared__ f16 tile[WW][73];            // [w][c], 73 to spread banks
  for (int idx = threadIdx.x; idx < 64*WW; idx += 256) {
    int cl = idx / WW, w = idx % WW;      // coalesced in w
    float v = x[((size_t)(b*CIN + c0 + cl)*HH + h)*WW + w];
    tile[w][cl] = (f16)v;
  }
  __syncthreads();
  f16* op = xp + (size_t)b*XPLANE + (size_t)((h+1)*58 + 1)*CIN + c0;
  for (int idx = threadIdx.x; idx < WW*16; idx += 256) {
    int w = idx >> 4, c4 = (idx & 15) << 2;   // coalesced in c
    f16x4 t = { tile[w][c4], tile[w][c4+1], tile[w][c4+2], tile[w][c4+3] };
    *(f16x4*)(op + (size_t)w*CIN + c4) = t;
  }
}

// ---------------------------------------------------------------------------
// Prepass 2: w (OIHW f32) -> sign -> f16, pre-tiled to the exact per-K-step
// LDS staging order: wt[s][co][cl], s = kidx*4 + cb, c = cb*32 + cl.
// Main kernel then stages B with perfectly contiguous 16 KB copies.
// ---------------------------------------------------------------------------
__global__ __launch_bounds__(256) void wprep_kernel(const float* __restrict__ w,
                                                    f16* __restrict__ wt) {
  int t = blockIdx.x*256 + threadIdx.x;   // 294912 total, grid exact
  int s  = t >> 13;                       // /8192  -> K-step
  int r  = t & 8191;
  int co = r >> 5;
  int cl = r & 31;
  int kidx = s >> 2;                      // kh*3+kw
  int c  = ((s & 3) << 5) + cl;
  float v = w[(size_t)co*1152 + c*9 + kidx];
  wt[t] = (f16)((v > 0.f) ? 1.f : (v < 0.f ? -1.f : 0.f));
}

// ---------------------------------------------------------------------------
// Main implicit-GEMM: tile 128 px x 256 co, K = 1152 (9 taps x 128 c), BK=32.
// 8 waves (2 px x 4 co), each wave 64x64 via mfma_f32_16x16x32_f16.
// A-operand = weights (rows=co), B-operand = x (cols=px) so the MFMA D
// layout has px on the fast lane dim -> coalesced NCHW stores.
// ---------------------------------------------------------------------------
__global__ __launch_bounds__(512, 2) void bconv_main(
    const f16* __restrict__ xp, const f16* __restrict__ wt,
    const float* __restrict__ bias, float* __restrict__ out) {
  __shared__ __align__(16) f16 Alds[128][40];   // [px][c]  (pad 32->40)
  __shared__ __align__(16) f16 Blds[256][40];   // [co][c]
  const int tid = threadIdx.x;
  const int p0  = blockIdx.x * 128;             // 784 tiles, exact

  // A-staging map: thread -> (pixel, 8-channel part); pixel coords hoisted.
  const int px_s = tid >> 2;
  const int part = tid & 3;
  const int p_g  = p0 + px_s;
  const int b_s  = p_g / HW;
  const int pos  = p_g % HW;
  const int hs   = pos / WW;
  const int ws_  = pos % WW;
  const long xbase = (long)b_s*XPLANE + (long)((hs+1)*58 + ws_ + 1)*CIN + part*8;

  const int wave = tid >> 6, lane = tid & 63;
  const int wpx = wave >> 2;        // 0..1 : which 64-px half
  const int wco = wave & 3;         // 0..3 : which 64-co quarter
  const int l15 = lane & 15, l4 = lane >> 4;

  f32x4 acc[4][4];                  // [i: co frag][j: px frag]
  #pragma unroll
  for (int i = 0; i < 4; ++i)
    #pragma unroll
    for (int j = 0; j < 4; ++j)
      acc[i][j] = (f32x4){0.f, 0.f, 0.f, 0.f};

  #pragma unroll 1
  for (int kidx = 0; kidx < 9; ++kidx) {
    const int dh = kidx/3 - 1, dw = kidx - (kidx/3)*3 - 1;
    const f16* xsrc = xp + (xbase + (long)(dh*58 + dw)*CIN);
    #pragma unroll 1
    for (int cb = 0; cb < 4; ++cb) {
      const int s = kidx*4 + cb;
      // ---- stage A (x patch): 512 thr x 16B = 128px x 32c ----
      f16x8 av = *(const f16x8*)(xsrc + cb*32);
      // ---- stage B (weights): contiguous 16 KB block ----
      const f16* wsrc = wt + (size_t)s*8192 + tid*16;
      f16x8 bv0 = *(const f16x8*)(wsrc);
      f16x8 bv1 = *(const f16x8*)(wsrc + 8);
      *(f16x8*)&Alds[px_s][part*8] = av;
      const int co_s = tid >> 1;
      const int cs   = (tid & 1) << 4;
      *(f16x8*)&Blds[co_s][cs]     = bv0;
      *(f16x8*)&Blds[co_s][cs + 8] = bv1;
      __syncthreads();
      // ---- fragments + 16 MFMA ----
      f16x8 xf[4], wf[4];
      #pragma unroll
      for (int j = 0; j < 4; ++j)
        xf[j] = *(const f16x8*)&Alds[wpx*64 + j*16 + l15][l4*8];
      #pragma unroll
      for (int i = 0; i < 4; ++i)
        wf[i] = *(const f16x8*)&Blds[wco*64 + i*16 + l15][l4*8];
      #pragma unroll
      for (int i = 0; i < 4; ++i)
        #pragma unroll
        for (int j = 0; j < 4; ++j)
          acc[i][j] = __builtin_amdgcn_mfma_f32_16x16x32_f16(wf[i], xf[j], acc[i][j], 0, 0, 0);
      __syncthreads();
    }
  }

  // Epilogue: D col (lane&15) = pixel -> 16 consecutive px per quarter-wave,
  // coalesced NCHW stores. Bias added from L1-cached fp32.
  #pragma unroll
  for (int j = 0; j < 4; ++j) {
    const int pg = p0 + wpx*64 + j*16 + l15;
    const int bb = pg / HW;
    const int pr = pg % HW;
    float* ob = out + (size_t)bb*(COUT*HW) + pr;
    #pragma unroll
    for (int i = 0; i < 4; ++i) {
      const int cb2 = wco*64 + i*16 + l4*4;
      #pragma unroll
      for (int r = 0; r < 4; ++r) {
        const int co = cb2 + r;
        ob[(size_t)co*HW] = acc[i][j][r] + bias[co];
      }
    }
  }
}

extern "C" void kernel_launch(void* const* d_in, const int* in_sizes, int n_in,
                              void* d_out, int out_size, void* d_ws, size_t ws_size,
                              hipStream_t stream) {
  const float* x    = (const float*)d_in[0];
  const float* w    = (const float*)d_in[1];
  const float* bias = (const float*)d_in[2];
  float* out = (float*)d_out;

  f16* xp = (f16*)d_ws;                       // 32*430592 halves = 27.56 MB
  f16* wt = xp + (size_t)32*XPLANE;           // 294912 halves    = 0.59 MB

  // ws is re-poisoned to 0xAA before every timed call: must zero the pads.
  hipMemsetAsync(d_ws, 0, (size_t)32*XPLANE*sizeof(f16), stream);
  xpad_kernel<<<3584, 256, 0, stream>>>(x, xp);
  wprep_kernel<<<1152, 256, 0, stream>>>(w, wt);
  bconv_main<<<784, 512, 0, stream>>>(xp, wt, bias, out);
}

// Round 2
// 207.032 us; speedup vs baseline: 1.1757x; 1.1757x over previous
//
#include <hip/hip_runtime.h>
#include <cstdint>
#include <cstddef>

typedef _Float16 f16;
typedef _Float16 f16x4 __attribute__((ext_vector_type(4)));
typedef _Float16 f16x8 __attribute__((ext_vector_type(8)));
typedef float    f32x4 __attribute__((ext_vector_type(4)));

#define CIN    128
#define COUT   256
#define HH     56
#define WW     56
#define HW     3136           // 56*56
#define PPDIM  3364           // 58*58 padded pixel plane
#define XPLANE (PPDIM*CIN)    // 430592 halves per batch image

__device__ __forceinline__ void gload16(const void* g, void* l) {
  __builtin_amdgcn_global_load_lds((const __attribute__((address_space(1))) unsigned int*)g,
                                   (__attribute__((address_space(3))) unsigned int*)l,
                                   16, 0, 0);
}

// ---------------------------------------------------------------------------
// Prepass 1: x (NCHW f32) -> zero-padded NHWC f16, INCLUDING all pad rows/cols
// (no memset needed). One block per (b, padded-row pr in 0..57).
// xp[b][pp][c], pp = pr*58 + pc; interior: pr=h+1, pc=w+1.
// LDS transpose tile[c][w] stride 65 halves (odd -> 2-way max bank aliasing).
// ---------------------------------------------------------------------------
__global__ __launch_bounds__(256) void xpad_kernel(const float* __restrict__ x,
                                                   f16* __restrict__ xp) {
  const int bid = blockIdx.x;             // 32*58 = 1856
  const int pr  = bid % 58;
  const int b   = bid / 58;
  const int tid = threadIdx.x;
  __shared__ f16 tile[128 * 65];

  const bool interior = (pr >= 1) && (pr <= 56);
  if (interior) {
    const int h = pr - 1;
    // 128 c x 14 w-quads = 1792 f32x4 loads (coalesced 224B runs per c-row)
    #pragma unroll
    for (int it = 0; it < 7; ++it) {
      int i  = it * 256 + tid;
      int c  = i / 14;
      int wq = i - c * 14;
      const float* src = x + (((size_t)(b * CIN + c) * HH + h) * WW + wq * 4);
      f32x4 v = *(const f32x4*)src;
      f16x4 t = { (f16)v.x, (f16)v.y, (f16)v.z, (f16)v.w };
      *(f16x4*)&tile[c * 65 + wq * 4] = t;
    }
  }
  __syncthreads();
  // 58 px x 16 c-groups = 928 f16x8 stores (fully contiguous per wave)
  f16* orow = xp + (size_t)b * XPLANE + (size_t)pr * 58 * CIN;
  for (int i = tid; i < 928; i += 256) {
    int px = i >> 4;
    int cg = i & 15;
    f16x8 v = {};
    if (interior && px >= 1 && px <= 56) {
      int w = px - 1;
      #pragma unroll
      for (int j = 0; j < 8; ++j) v[j] = tile[(cg * 8 + j) * 65 + w];
    }
    *(f16x8*)(orow + (size_t)px * CIN + cg * 8) = v;
  }
}

// ---------------------------------------------------------------------------
// Prepass 2: w (OIHW f32) -> sign -> f16, stored as the EXACT (pre-swizzled)
// LDS image the main kernel stages with linear global_load_lds.
// Image per K-step s (18 steps of BK=64): 256 co rows x 128 B, with the m201
// st-swizzle baked in: kbyte = (obyte&127) ^ ((co&4)<<3).
// K order: k = kidx*128 + c ; step s covers k in [s*64, s*64+64).
// ---------------------------------------------------------------------------
__global__ __launch_bounds__(256) void wprep_kernel(const float* __restrict__ w,
                                                    f16* __restrict__ wt) {
  int t = blockIdx.x * 256 + threadIdx.x;   // 294912 exact
  int s     = t >> 14;                      // K-step (16384 halves each)
  int hidx  = t & 16383;
  int co    = hidx >> 6;
  int khalf = (hidx & 63) ^ ((co & 4) << 2);  // un-swizzle to logical k
  int kidx  = s >> 1;
  int c     = ((s & 1) << 6) + khalf;
  float v = w[(size_t)co * 1152 + c * 9 + kidx];
  wt[t] = (f16)((v > 0.f) ? 1.f : (v < 0.f ? -1.f : 0.f));
}

// ---------------------------------------------------------------------------
// Main implicit-GEMM: tile 128 px x 256 co, K=1152, BK=64 (18 steps).
// 8 waves (2 px x 4 co), each 64x64 via mfma_f32_16x16x32_f16.
// Staging: global_load_lds dwordx4, LDS images carry m201 st-swizzle
// (byte bit5 ^= row bit2) via pre-swizzled per-lane SOURCE addresses.
// ---------------------------------------------------------------------------
__global__ __launch_bounds__(512) void bconv_main(
    const f16* __restrict__ xp, const f16* __restrict__ wt,
    const float* __restrict__ bias, float* __restrict__ out) {
  __shared__ __align__(16) f16 Alds[128 * 64];   // 16 KB  [px][64 halves]
  __shared__ __align__(16) f16 Blds[256 * 64];   // 32 KB  [co][64 halves]
  const int tid = threadIdx.x;
  const int p0  = blockIdx.x * 128;              // 784 tiles exact

  // ---- staging maps (hoisted) ----
  const int wave = tid >> 6, lane = tid & 63;
  // A: image offset o = tid*16 (+8192); px_local = o>>7, 16B slot = tid&7
  const int pxl  = tid >> 3;                     // 0..63  (second load: +64)
  const int kx_s = ((tid & 7) << 4) ^ ((pxl & 4) << 3);  // swizzled k-byte
  const int pga  = p0 + pxl;
  const int pgb  = pga + 64;
  const int ba = pga / HW, ra = pga % HW;
  const int bb = pgb / HW, rb = pgb % HW;
  const int ha = ra / WW, wa = ra % WW;
  const int hb = rb / WW, wb = rb % WW;
  const char* xpB = (const char*)xp;
  const char* srcA0 = xpB + 2 * ((size_t)ba * XPLANE + (size_t)((ha + 1) * 58 + wa + 1) * CIN) + kx_s;
  const char* srcA1 = xpB + 2 * ((size_t)bb * XPLANE + (size_t)((hb + 1) * 58 + wb + 1) * CIN) + kx_s;
  char* AldsB = (char*)Alds;
  char* BldsB = (char*)Blds;
  char* dstA0 = AldsB + (wave << 10);
  char* dstA1 = AldsB + 8192 + (wave << 10);
  const char* wtB = (const char*)wt + (tid << 4);
  char* dstB = BldsB + (wave << 10);

  // ---- fragment maps ----
  const int wpx = wave >> 2;       // 0..1
  const int wco = wave & 3;        // 0..3
  const int l15 = lane & 15, l4 = lane >> 4;
  const int kxr = (l15 & 4) << 3;  // read-side swizzle (row bit2 -> byte bit5)
  const int rA = ((wpx << 6) + l15) << 7;   // byte row base in Alds
  const int rB = ((wco << 6) + l15) << 7;   // byte row base in Blds

  f32x4 acc[4][4];
  #pragma unroll
  for (int i = 0; i < 4; ++i)
    #pragma unroll
    for (int j = 0; j < 4; ++j) acc[i][j] = (f32x4){0.f, 0.f, 0.f, 0.f};

  #pragma unroll 1
  for (int s = 0; s < 18; ++s) {
    const int kidx = s >> 1, ch = s & 1;
    const int dh = kidx / 3 - 1, dw = kidx - (kidx / 3) * 3 - 1;
    const long toff = (long)(dh * 58 + dw) * 256 + ch * 128;
    gload16(srcA0 + toff, dstA0);
    gload16(srcA1 + toff, dstA1);
    const char* ws = wtB + (size_t)s * 32768;
    gload16(ws,         dstB);
    gload16(ws + 8192,  dstB + 8192);
    gload16(ws + 16384, dstB + 16384);
    gload16(ws + 24576, dstB + 24576);
    __syncthreads();

    #pragma unroll
    for (int kk = 0; kk < 2; ++kk) {
      const int ko = ((kk << 6) + (l4 << 4)) ^ kxr;
      f16x8 xf[4], wf[4];
      #pragma unroll
      for (int j = 0; j < 4; ++j)
        xf[j] = *(const f16x8*)(AldsB + rA + (j << 11) + ko);
      #pragma unroll
      for (int i = 0; i < 4; ++i)
        wf[i] = *(const f16x8*)(BldsB + rB + (i << 11) + ko);
      #pragma unroll
      for (int i = 0; i < 4; ++i)
        #pragma unroll
        for (int j = 0; j < 4; ++j)
          acc[i][j] = __builtin_amdgcn_mfma_f32_16x16x32_f16(wf[i], xf[j], acc[i][j], 0, 0, 0);
    }
    __syncthreads();
  }

  // Epilogue: D col (lane&15) = pixel; coalesced 64B runs along px.
  #pragma unroll
  for (int j = 0; j < 4; ++j) {
    const int pg = p0 + wpx * 64 + j * 16 + l15;
    const int bo = pg / HW;
    const int pr = pg % HW;
    float* ob = out + (size_t)bo * (COUT * HW) + pr;
    #pragma unroll
    for (int i = 0; i < 4; ++i) {
      const int cb2 = wco * 64 + i * 16 + l4 * 4;
      #pragma unroll
      for (int r = 0; r < 4; ++r) {
        const int co = cb2 + r;
        ob[(size_t)co * HW] = acc[i][j][r] + bias[co];
      }
    }
  }
}

extern "C" void kernel_launch(void* const* d_in, const int* in_sizes, int n_in,
                              void* d_out, int out_size, void* d_ws, size_t ws_size,
                              hipStream_t stream) {
  const float* x    = (const float*)d_in[0];
  const float* w    = (const float*)d_in[1];
  const float* bias = (const float*)d_in[2];
  float* out = (float*)d_out;

  f16* xp = (f16*)d_ws;                       // 32*430592 halves = 27.56 MB
  f16* wt = xp + (size_t)32 * XPLANE;         // 294912 halves    = 0.59 MB

  xpad_kernel<<<1856, 256, 0, stream>>>(x, xp);     // writes ALL of xp incl pads
  wprep_kernel<<<1152, 256, 0, stream>>>(w, wt);    // writes ALL of wt
  bconv_main<<<784, 512, 0, stream>>>(xp, wt, bias, out);
}